// Round 5
// baseline (1112295.117 us; speedup 1.0000x reference)
//
#include <hip/hip_runtime.h>

// ContinuousGRULayer round 5: cooperative groups with LDS-resident weight
// shards (spill-proof redo of round 4, whose VGPR-resident weights spilled).
//   16 groups x 16 WGs = 256 WGs x 1024 threads. WG (g,w) owns neurons
//   [32w,32w+32) (all three gates, full K rows -> no cross-WG reductions)
//   for chains [8g,8g+8). Recurrent+input weights live in LDS (~149 KB).
//   Per eval: A(z,r) -> publish rh slice -> barrier -> B(g)+RK4 -> publish h
//   -> barrier. Exchange via d_ws; round-4's validated fence+atomic barrier.

namespace {
constexpr int kT = 512, kF = 128, kH = 512, kFH = 640;
constexpr int NGRP = 16;   // chain groups
constexpr int WPG = 16;    // WGs per group
constexpr int MC = 8;      // chains per group
constexpr int NJ = 32;     // neurons per WG
constexpr size_t HX_OFF = 0;                              // [NGRP][MC][kH] f16
constexpr size_t HX_BYTES = (size_t)NGRP * MC * kH * 2;   // 128 KB
constexpr size_t RHX_OFF = HX_OFF + HX_BYTES;             // 128 KB
constexpr size_t CTR_OFF = RHX_OFF + HX_BYTES;            // NGRP ctrs, 64B apart
}  // namespace

typedef _Float16 h2_t __attribute__((ext_vector_type(2)));

__device__ __forceinline__ unsigned short f2h(float f) {
  return __builtin_bit_cast(unsigned short, (_Float16)f);
}
__device__ __forceinline__ unsigned pack2h(float a, float b) {
  return (unsigned)f2h(a) | ((unsigned)f2h(b) << 16);
}
__device__ __forceinline__ float h2f(unsigned short u) {
  return (float)__builtin_bit_cast(_Float16, u);
}
__device__ __forceinline__ float dot2(unsigned w, unsigned h, float acc) {
  return __builtin_amdgcn_fdot2(__builtin_bit_cast(h2_t, w),
                                __builtin_bit_cast(h2_t, h), acc, false);
}
__device__ __forceinline__ float dot2x4(uint4 w, uint4 h, float acc) {
  acc = dot2(w.x, h.x, acc); acc = dot2(w.y, h.y, acc);
  acc = dot2(w.z, h.z, acc); acc = dot2(w.w, h.w, acc);
  return acc;
}
// 8 consecutive f32 -> uint4 of 8 f16
__device__ __forceinline__ uint4 pk8(const float* s) {
  const float4 a = *(const float4*)s;
  const float4 b = *(const float4*)(s + 4);
  uint4 o;
  o.x = pack2h(a.x, a.y); o.y = pack2h(a.z, a.w);
  o.z = pack2h(b.x, b.y); o.w = pack2h(b.z, b.w);
  return o;
}

__global__ void init_ws(unsigned* ws_u) {
  const unsigned i = blockIdx.x * 256 + threadIdx.x;
  if (i < HX_BYTES / 4) ws_u[HX_OFF / 4 + i] = 0;   // h0 = 0
  if (i < 256) ws_u[CTR_OFF / 4 + i] = 0;           // barrier counters
}

__device__ __forceinline__ void bar_arrive(unsigned* c) {
  __threadfence();
  __syncthreads();
  if (threadIdx.x == 0) atomicAdd(c, 1u);
}
__device__ __forceinline__ void bar_wait(unsigned* c, unsigned target) {
  if (threadIdx.x == 0) {
    while (__hip_atomic_load(c, __ATOMIC_RELAXED, __HIP_MEMORY_SCOPE_AGENT) <
           target) {
      __builtin_amdgcn_s_sleep(1);
    }
  }
  __syncthreads();
  __threadfence();
}

__global__ __launch_bounds__(1024, 1) void cgru_coop(
    const float* __restrict__ x, const float* __restrict__ td,
    const float* __restrict__ Wz, const float* __restrict__ bz,
    const float* __restrict__ Wr, const float* __restrict__ br,
    const float* __restrict__ Wg, const float* __restrict__ bg,
    void* __restrict__ ws, float* __restrict__ out) {
  // row pads (+1 uint4) break power-of-2 bank strides
  __shared__ uint4 WhL[2][NJ][65];   // z,r recurrent rows   66,560 B
  __shared__ uint4 WgL[NJ][65];      // g recurrent (k2-interleaved) 33,280 B
  __shared__ uint4 WxL[3][NJ][17];   // x-part rows          26,112 B
  __shared__ uint4 hT[MC][65];       // stage-h tile          8,320 B
  __shared__ uint4 rhT[MC][65];      // r*h tile (perm)       8,320 B
  __shared__ uint4 xtL[MC][17];      // x_t tile              2,176 B
  __shared__ float axb[3][NJ][MC];   // x-part dots + bias    3,072 B
  __shared__ float zbuf[NJ][MC];     // z per (n,m)           1,024 B
  __shared__ float bbuf[3][NJ];
  __shared__ float dtL[MC];

  const int blk = blockIdx.x;
  // group swizzle: members of a group share blk%8 (XCD round-robin heuristic)
  const int grp = (blk & 7) * 2 + (blk >> 7);
  const int w   = (blk >> 3) & 15;
  const int tid = threadIdx.x;

  unsigned short* hx =
      (unsigned short*)((char*)ws + HX_OFF) + (size_t)grp * MC * kH;
  unsigned short* rhx =
      (unsigned short*)((char*)ws + RHX_OFF) + (size_t)grp * MC * kH;
  const uint4* hx4  = (const uint4*)hx;
  const uint4* rhx4 = (const uint4*)rhx;
  unsigned* ctr = (unsigned*)((char*)ws + CTR_OFF + (size_t)grp * 64);

  // ---- load weight shard -> LDS (once) ----
  for (int q = tid; q < 2 * NJ * 64; q += 1024) {       // z, r recurrent
    const int gate = q >> 11, rem = q & 2047, n = rem >> 6, c = rem & 63;
    const float* W = gate ? Wr : Wz;
    WhL[gate][n][c] = pk8(W + (size_t)(NJ * w + n) * kFH + kF + 8 * c);
  }
  for (int q = tid; q < NJ * 64; q += 1024) {           // g recurrent
    const int n = q >> 6, c = q & 63;                   // chunk c = k2*16+p
    WgL[n][(c & 15) * 4 + (c >> 4)] =
        pk8(Wg + (size_t)(NJ * w + n) * kFH + kF + 8 * c);
  }
  for (int q = tid; q < 3 * NJ * 16; q += 1024) {       // x-part
    const int gate = q >> 9, rem = q & 511, n = rem >> 4, c = rem & 15;
    const float* W = (gate == 0) ? Wz : (gate == 1) ? Wr : Wg;
    WxL[gate][n][c] = pk8(W + (size_t)(NJ * w + n) * kFH + 8 * c);
  }
  if (tid < 96) {
    const int gate = tid >> 5, n = tid & 31;
    bbuf[gate][n] =
        ((gate == 0) ? bz : (gate == 1) ? br : bg)[NJ * w + n];
  }

  float hb = 0.f, hs = 0.f, kacc = 0.f;   // commit-lane state (k2==0 lanes)
  unsigned ep = 0;

  for (int t = 0; t < kT; ++t) {
    if (tid < 512) {   // stage x_t (8 chains), f16-packed
      const int m = tid >> 6, c2 = tid & 63;
      const float2 xv = *(const float2*)(
          x + ((size_t)(MC * grp + m) * kT + t) * kF + 2 * c2);
      ((unsigned*)xtL)[m * 68 + c2] = pack2h(xv.x, xv.y);
    }
    if (tid < MC)
      dtL[tid] = fminf(td[(size_t)(MC * grp + tid) * kT + t], 1.0f) * 0.5f;
    __syncthreads();
    if (tid < 768) {   // x-part dots + bias, once per timestep
      const int gate = tid >> 8, n = (tid >> 3) & 31, m = tid & 7;
      float a = bbuf[gate][n];
#pragma unroll
      for (int p = 0; p < 16; ++p)
        a = dot2x4(WxL[gate][n][p], xtL[m][p], a);
      axb[gate][n][m] = a;
    }
    // axb/xt hazards covered by the syncthreads inside staging/barriers below

    for (int e = 0; e < 8; ++e) {   // 2 ODE steps x 4 RK4 stages
      const int s = e & 3;
      // ---- phase A: z,r over h ----
      if (ep) bar_wait(ctr, WPG * ep);
      if (tid < 512) {   // stage h tile (zeros from init_ws at t=0,e=0)
        const int m = tid >> 6, c = tid & 63;
        hT[m][c] = hx4[tid];
      }
      __syncthreads();
      {
        const int gate = tid >> 9, n = (tid >> 4) & 31,
                  m = (tid >> 1) & 7, k = tid & 1;
        float a = 0.f;
#pragma unroll 8
        for (int p = 0; p < 32; ++p)
          a = dot2x4(WhL[gate][n][k * 32 + p], hT[m][k * 32 + p], a);
        a += __shfl_xor(a, 1);
        if (k == 0) {
          a += axb[gate][n][m];
          if (gate == 0) {
            zbuf[n][m] = 1.0f / (1.0f + __expf(-a));
          } else {
            const float r = 1.0f / (1.0f + __expf(-a));
            const float hv =
                h2f(((const unsigned short*)hT)[m * 520 + NJ * w + n]);
            rhx[(size_t)m * kH + NJ * w + n] = f2h(r * hv);
          }
        }
      }
      bar_arrive(ctr); ++ep;
      // ---- phase B: g over rh, RK4 commit ----
      bar_wait(ctr, WPG * ep);
      if (tid < 512) {   // stage rh tile, k2-interleaved to match WgL
        const int m = tid >> 6, c = tid & 63;
        rhT[m][(c & 15) * 4 + (c >> 4)] = rhx4[tid];
      }
      __syncthreads();
      {
        const int n = tid >> 5, m = (tid >> 2) & 7, k2 = tid & 3;
        float a = 0.f;
#pragma unroll 8
        for (int p = 0; p < 16; ++p)
          a = dot2x4(WgL[n][p * 4 + k2], rhT[m][p * 4 + k2], a);
        a += __shfl_xor(a, 1);
        a += __shfl_xor(a, 2);
        if (k2 == 0) {
          const float g = tanhf(a + axb[2][n][m]);
          const float kk = (1.0f - zbuf[n][m]) * (g - hs);
          if (s == 0) kacc = kk;
          else kacc += ((s == 3) ? 1.0f : 2.0f) * kk;
          const float dtv = dtL[m];
          float nxt;
          if (s < 3) {
            nxt = fmaf((s == 2 ? 1.0f : 0.5f) * dtv, kk, hb);
          } else {
            hb = fmaf(dtv * (1.0f / 6.0f), kacc, hb);
            nxt = hb;
          }
          hs = nxt;
          hx[(size_t)m * kH + NJ * w + n] = f2h(nxt);
          if (e == 7)
            out[((size_t)(MC * grp + m) * kT + t) * kH + NJ * w + n] = hb;
        }
      }
      bar_arrive(ctr); ++ep;
    }
  }
}

extern "C" void kernel_launch(void* const* d_in, const int* in_sizes, int n_in,
                              void* d_out, int out_size, void* d_ws, size_t ws_size,
                              hipStream_t stream) {
  const float* x  = (const float*)d_in[0];
  const float* td = (const float*)d_in[1];
  const float* Wz = (const float*)d_in[2];
  const float* bz = (const float*)d_in[3];
  const float* Wr = (const float*)d_in[4];
  const float* br = (const float*)d_in[5];
  const float* Wg = (const float*)d_in[6];
  const float* bg = (const float*)d_in[7];
  float* out = (float*)d_out;

  init_ws<<<(int)((HX_BYTES / 4 + 255) / 256), 256, 0, stream>>>(
      (unsigned*)d_ws);
  cgru_coop<<<NGRP * WPG, 1024, 0, stream>>>(
      x, td, Wz, bz, Wr, br, Wg, bg, d_ws, out);
}

// Round 6
// 55285.358 us; speedup vs baseline: 20.1192x; 20.1192x over previous
//
#include <hip/hip_runtime.h>

// ContinuousGRULayer round 6: round-2 structure (1 chain per WG, gate-split,
// LDS h-broadcast, dot2-f16) + CU-resident weight offload:
//   - 8 z/r K-slices in registers (named vars, 32 VGPRs/thread)
//   - 9 z/r K-slices in LDS (WL[9][1024], 144 KB, conflict-free ds_read_b128)
//   - remaining 47 z/r + 32 g slices streamed from L2 (1.23 MB/eval vs 1.5).
// No cross-WG sync anywhere (rounds 4/5 proved device-scope barriers cost
// ~100 us on this part). 128 WGs x 1024 threads.

namespace {
constexpr int kB = 128, kT = 512, kF = 128, kH = 512, kFH = 640;
// d_ws layout in uint4 (16B = 8 f16) units: slice p of neuron j at
// [region + p*kH + j] -> lane j reads 16B, wave-coalesced.
constexpr int XS = (kF / 8) * kH;          // 8192 per x-gate
constexpr int HS = (kH / 8) * kH;          // 32768 per h-gate
constexpr int OXZ = 0, OXR = XS, OXG = 2 * XS;
constexpr int OHZ = 3 * XS, OHR = 3 * XS + HS, OHG = 3 * XS + 2 * HS;
constexpr int OTOT = 3 * XS + 3 * HS;      // 122880 * 16B = 1.97 MB
constexpr int RREG = 8;    // register-resident z/r slices (k4 = 0..7)
constexpr int RLDS = 9;    // LDS-resident z/r slices      (k4 = 8..16)
constexpr int RES = RREG + RLDS;           // 17; streamed k4 = 17..63
}  // namespace

typedef _Float16 h2_t __attribute__((ext_vector_type(2)));

__device__ __forceinline__ unsigned short f2h(float f) {
  return __builtin_bit_cast(unsigned short, (_Float16)f);
}
__device__ __forceinline__ unsigned pack2h(float a, float b) {
  return (unsigned)f2h(a) | ((unsigned)f2h(b) << 16);
}
__device__ __forceinline__ float h2f(unsigned short u) {
  return (float)__builtin_bit_cast(_Float16, u);
}
__device__ __forceinline__ float dot2(unsigned w, unsigned h, float acc) {
  return __builtin_amdgcn_fdot2(__builtin_bit_cast(h2_t, w),
                                __builtin_bit_cast(h2_t, h), acc, false);
}
__device__ __forceinline__ float dot2x4(uint4 w, uint4 h, float acc) {
  acc = dot2(w.x, h.x, acc); acc = dot2(w.y, h.y, acc);
  acc = dot2(w.z, h.z, acc); acc = dot2(w.w, h.w, acc);
  return acc;
}

// ---- weight pre-pack: f32 [H][F+H] -> f16 k8-transposed regions in d_ws ----
__global__ void convert_weights(const float* __restrict__ Wz,
                                const float* __restrict__ Wr,
                                const float* __restrict__ Wg,
                                uint4* __restrict__ ws) {
  int tid = blockIdx.x * 256 + threadIdx.x;
  if (tid >= OTOT) return;
  const float* W;
  int cbase, p, j;
  if (tid < 3 * XS) {
    int m = tid / XS, l = tid - m * XS;
    W = (m == 0) ? Wz : (m == 1) ? Wr : Wg;
    cbase = 0; p = l / kH; j = l - p * kH;
  } else {
    int t2 = tid - 3 * XS;
    int m = t2 / HS, l = t2 - m * HS;
    W = (m == 0) ? Wz : (m == 1) ? Wr : Wg;
    cbase = kF; p = l / kH; j = l - p * kH;
  }
  const float* s = W + (size_t)j * kFH + cbase + p * 8;
  uint4 o;
  o.x = pack2h(s[0], s[1]); o.y = pack2h(s[2], s[3]);
  o.z = pack2h(s[4], s[5]); o.w = pack2h(s[6], s[7]);
  ws[tid] = o;
}

__global__ __launch_bounds__(1024, 4) void cgru_res(
    const float* __restrict__ x, const float* __restrict__ td,
    const float* __restrict__ bz, const float* __restrict__ br,
    const float* __restrict__ bg, const uint4* __restrict__ ws,
    float* __restrict__ out) {
  __shared__ __align__(16) uint4 WL[RLDS][1024];   // 147,456 B resident slices
  __shared__ __align__(16) unsigned hpk[kH / 2];   // stage h, k-packed f16
  __shared__ __align__(16) unsigned rpk[kH / 2];   // r*h,     k-packed f16
  __shared__ __align__(16) unsigned xpk[kF / 2];   // x_t,     k-packed f16
  __shared__ float gpart[kH];                      // half1's g partials

  const int b = blockIdx.x;
  const int tid = threadIdx.x;
  const int j = tid & (kH - 1);
  const int half = tid >> 9;

  const uint4* __restrict__ wA = ws + (half ? OHR : OHZ) + j;  // z or r rows
  const uint4* __restrict__ wG = ws + OHG + half * (kH / 16) * kH + j;
  const uint4* __restrict__ wxz = ws + OXZ + j;
  const uint4* __restrict__ wxr = ws + OXR + j;
  const uint4* __restrict__ wxg = ws + OXG + j;

  // ---- resident preload: 8 slices -> named registers, 9 slices -> LDS ----
  const uint4 a0 = wA[0 * kH], a1 = wA[1 * kH], a2 = wA[2 * kH],
              a3 = wA[3 * kH], a4 = wA[4 * kH], a5 = wA[5 * kH],
              a6 = wA[6 * kH], a7 = wA[7 * kH];
#pragma unroll
  for (int s = 0; s < RLDS; ++s) WL[s][tid] = wA[(RREG + s) * kH];

  const float bias = half ? br[j] : bz[j];
  const float bgv = bg[j];

  float hb = 0.f, hs = 0.f;          // committed / stage h[j] (half0 lanes)
  if (tid < kH / 2) hpk[tid] = 0;    // h = 0

  for (int t = 0; t < kT; ++t) {
    if (tid < kF / 2) {              // stage x_t, f16 k-packed
      const float2 xv =
          *(const float2*)(x + ((size_t)b * kT + t) * kF + 2 * tid);
      xpk[tid] = pack2h(xv.x, xv.y);
    }
    __syncthreads();                 // xpk (and initial hpk) visible

    // ---- x-part + bias, reused by all 8 RK4 evals of this timestep ----
    const uint4* xp4 = (const uint4*)xpk;
    float ax = bias;                 // az (half0) or ar (half1)
    {
      const uint4* __restrict__ wx = half ? wxr : wxz;
#pragma unroll
      for (int p = 0; p < 16; ++p) ax = dot2x4(wx[p * kH], xp4[p], ax);
    }
    float agp = half ? 0.f : bgv;    // g x-part, K split across halves
#pragma unroll
    for (int p = 0; p < 8; ++p)
      agp = dot2x4(wxg[(half * 8 + p) * kH], xp4[half * 8 + p], agp);
    const float dtv = fminf(td[(size_t)b * kT + t], 1.0f) * 0.5f;

    float kacc = 0.f;
    for (int e = 0; e < 8; ++e) {    // 2 ODE steps x 4 RK4 stages
      const int s = e & 3;
      const uint4* hp4 = (const uint4*)hpk;   // wave-uniform -> broadcast
      // ---- z/r dot: 8 reg + 9 LDS + 47 streamed slices ----
      float acc = ax;
      acc = dot2x4(a0, hp4[0], acc); acc = dot2x4(a1, hp4[1], acc);
      acc = dot2x4(a2, hp4[2], acc); acc = dot2x4(a3, hp4[3], acc);
      acc = dot2x4(a4, hp4[4], acc); acc = dot2x4(a5, hp4[5], acc);
      acc = dot2x4(a6, hp4[6], acc); acc = dot2x4(a7, hp4[7], acc);
#pragma unroll
      for (int q = 0; q < RLDS; ++q)
        acc = dot2x4(WL[q][tid], hp4[RREG + q], acc);
#pragma unroll 8
      for (int k = RES; k < kH / 8; ++k)
        acc = dot2x4(wA[k * kH], hp4[k], acc);

      float z = 0.f;
      if (half == 0) {
        z = 1.0f / (1.0f + __expf(-acc));
      } else {
        const float r = 1.0f / (1.0f + __expf(-acc));
        const float hv = h2f(((const unsigned short*)hpk)[j]);
        ((unsigned short*)rpk)[j] = f2h(r * hv);
      }
      __syncthreads();               // #1: rh visible; hpk reads done

      // ---- g dot over rh: 32 streamed slices (K-half per half) ----
      const uint4* rp4 = (const uint4*)rpk;
      float ga = agp;
#pragma unroll 8
      for (int k = 0; k < kH / 16; ++k)
        ga = dot2x4(wG[k * kH], rp4[half * (kH / 16) + k], ga);
      if (half == 1) gpart[j] = ga;
      __syncthreads();               // #2: gpart visible; rpk reads done

      if (half == 0) {
        const float g = tanhf(ga + gpart[j]);
        const float kk = (1.0f - z) * (g - hs);
        kacc = (s == 0) ? kk : kacc + ((s == 3) ? 1.0f : 2.0f) * kk;
        float nxt;
        if (s < 3) {
          nxt = fmaf((s == 2 ? 1.0f : 0.5f) * dtv, kk, hb);
        } else {
          hb = fmaf(dtv * (1.0f / 6.0f), kacc, hb);
          nxt = hb;
        }
        ((unsigned short*)hpk)[j] = f2h(nxt);
        hs = nxt;
      }
      __syncthreads();               // #3: new h visible
    }

    if (half == 0) out[((size_t)b * kT + t) * kH + j] = hb;  // coalesced
  }
}

extern "C" void kernel_launch(void* const* d_in, const int* in_sizes, int n_in,
                              void* d_out, int out_size, void* d_ws, size_t ws_size,
                              hipStream_t stream) {
  const float* x  = (const float*)d_in[0];
  const float* td = (const float*)d_in[1];
  const float* Wz = (const float*)d_in[2];
  const float* bz = (const float*)d_in[3];
  const float* Wr = (const float*)d_in[4];
  const float* br = (const float*)d_in[5];
  const float* Wg = (const float*)d_in[6];
  const float* bg = (const float*)d_in[7];
  float* out = (float*)d_out;

  convert_weights<<<(OTOT + 255) / 256, 256, 0, stream>>>(
      Wz, Wr, Wg, (uint4*)d_ws);
  cgru_res<<<kB, 1024, 0, stream>>>(
      x, td, bz, br, bg, (const uint4*)d_ws, out);
}